// Round 3
// baseline (828.550 us; speedup 1.0000x reference)
//
#include <hip/hip_runtime.h>
#include <hip/hip_bf16.h>
#include <cstdint>
#include <cstddef>

#define SEQ    4096
#define HEADS  32
#define HD     128
#define HIDDEN 2048
#define NINNER 4096
#define BLK    256
#define NB     16

typedef __attribute__((ext_vector_type(8)))  __bf16 bf16x8;
typedef __attribute__((ext_vector_type(4)))  __bf16 bf16x4;
typedef __attribute__((ext_vector_type(4)))  float  f32x4;
typedef __attribute__((ext_vector_type(16))) float  f32x16;

#define MFMA16(a,b,c) __builtin_amdgcn_mfma_f32_16x16x32_bf16((a),(b),(c),0,0,0)
#define MFMA32(a,b,c) __builtin_amdgcn_mfma_f32_32x32x16_bf16((a),(b),(c),0,0,0)

typedef __attribute__((address_space(1))) const unsigned int gu32;
typedef __attribute__((address_space(3))) unsigned int lu32;

__device__ __forceinline__ void gld16(void* lds, const void* g){
    __builtin_amdgcn_global_load_lds((gu32*)g, (lu32*)lds, 16, 0, 0);
}

__device__ __forceinline__ float slope_for_head(int h){
    return exp2f(-0.25f*(float)(h+1)) * 1.00001f;
}

// ---------------------------------------------------------------- prep: cast hs + 3 weight transposes, one launch
__device__ __forceinline__ void tcast_block(const float* __restrict__ W, __bf16* __restrict__ Wt,
                                            int K, int N, int bx, int by, __bf16 (*t)[72], int tid){
    const int n0 = bx*64, k0 = by*64;
    const int r = tid >> 4, c4 = tid & 15;
    #pragma unroll
    for (int i = 0; i < 4; i++){
        int k = r + i*16;
        float4 v = *(const float4*)(W + (size_t)(k0 + k)*N + n0 + c4*4);
        t[c4*4+0][k] = (__bf16)v.x;
        t[c4*4+1][k] = (__bf16)v.y;
        t[c4*4+2][k] = (__bf16)v.z;
        t[c4*4+3][k] = (__bf16)v.w;
    }
    __syncthreads();
    #pragma unroll
    for (int j = 0; j < 2; j++){
        int idx = tid + j*256;
        int n = idx >> 3, c8 = idx & 7;
        bf16x8 val = *(const bf16x8*)&t[n][c8*8];
        *(bf16x8*)(Wt + (size_t)(n0 + n)*K + k0 + c8*8) = val;
    }
}

__global__ __launch_bounds__(256)
void prep_all(const float* __restrict__ hs, __bf16* __restrict__ hsb,
              const float* __restrict__ Wqkv, __bf16* __restrict__ WqkvT,
              const float* __restrict__ Wgate, __bf16* __restrict__ WgateT,
              const float* __restrict__ Wout, __bf16* __restrict__ WoutT)
{
    __shared__ __align__(16) __bf16 t[64][72];
    const int tid = threadIdx.x;
    int id = blockIdx.x;
    if (id < 8192){
        int i = (id*256 + tid)*4;
        float4 v = *(const float4*)(hs + i);
        bf16x4 o;
        o[0] = (__bf16)v.x; o[1] = (__bf16)v.y; o[2] = (__bf16)v.z; o[3] = (__bf16)v.w;
        *(bf16x4*)(hsb + i) = o;
    } else if (id < 14336){
        int j = id - 8192;
        tcast_block(Wqkv, WqkvT, 2048, 12288, j % 192, j / 192, t, tid);
    } else if (id < 16384){
        int j = id - 14336;
        tcast_block(Wgate, WgateT, 2048, 4096, j % 64, j / 64, t, tid);
    } else {
        int j = id - 16384;
        tcast_block(Wout, WoutT, 4096, 2048, j % 32, j / 32, t, tid);
    }
}

// ---------------------------------------------------------------- GEMM (32x32x16 MFMA) C = A @ Bt^T
// A [M][K] bf16, Bt [N][K] bf16. 128x128 tile, BK=64, XOR-swizzled LDS.
// EPI 0: fused qkv+gate, N=16384. bn<96: silu -> q/k/v scatter (k also decayed->kT, v->vT transposed);
//        bn>=96: sigmoid -> sgate. Grid flat 4096, swizzled (bm fastest, 16-bn panels).
// EPI 2: f32 [M][N]. Grid flat 512 (bm fastest).
template<int EPI>
__global__ __launch_bounds__(256,2)
void gemm32(const __bf16* __restrict__ A, const __bf16* __restrict__ Bt,
            float* __restrict__ Cf,
            __bf16* __restrict__ qbuf, __bf16* __restrict__ kbuf,
            __bf16* __restrict__ kT,   __bf16* __restrict__ vT,
            __bf16* __restrict__ sgate,
            int M, int N, int K)
{
    __shared__ __align__(16) __bf16 a_lds[128*64];
    __shared__ __align__(16) __bf16 b_lds[128*64];
    const int tid  = threadIdx.x;
    const int lane = tid & 63;
    const int w    = tid >> 6;
    const int ml   = lane & 31;      // 32x32 row/col within frag
    const int half = lane >> 5;
    const int wm = w & 1, wn = w >> 1;

    int bm, bn;
    if constexpr (EPI == 0){
        int id = blockIdx.x;
        bm = id & 31;
        bn = (id >> 9)*16 + ((id >> 5) & 15);
    } else {
        bm = blockIdx.x & 31;
        bn = blockIdx.x >> 5;
    }

    f32x16 acc[2][2];
    #pragma unroll
    for (int i = 0; i < 2; i++)
        #pragma unroll
        for (int j = 0; j < 2; j++)
            #pragma unroll
            for (int e = 0; e < 16; e++) acc[i][j][e] = 0.f;

    const int r8 = lane >> 3;
    const int qs = (lane & 7) ^ r8;
    const int sw = ml & 7;
    const __bf16* Abase = A  + (size_t)bm*128*K;
    const __bf16* Bbase = Bt + (size_t)bn*128*K;

    for (int kb = 0; kb < K; kb += 64){
        #pragma unroll
        for (int t = 0; t < 4; t++){
            int ch = t*4 + w;
            gld16(a_lds + ch*512, Abase + (size_t)(ch*8 + r8)*K + kb + qs*8);
            gld16(b_lds + ch*512, Bbase + (size_t)(ch*8 + r8)*K + kb + qs*8);
        }
        __syncthreads();
        #pragma unroll
        for (int kst = 0; kst < 4; kst++){
            const int g = ((kst*2 + half) ^ sw)*8;
            bf16x8 af[2];
            #pragma unroll
            for (int mt = 0; mt < 2; mt++)
                af[mt] = *(const bf16x8*)&a_lds[(wm*64 + mt*32 + ml)*64 + g];
            #pragma unroll
            for (int nt = 0; nt < 2; nt++){
                bf16x8 bfv = *(const bf16x8*)&b_lds[(wn*64 + nt*32 + ml)*64 + g];
                #pragma unroll
                for (int mt = 0; mt < 2; mt++)
                    acc[mt][nt] = MFMA32(af[mt], bfv, acc[mt][nt]);
            }
        }
        __syncthreads();
    }

    // C/D layout (verified): col = lane&31, row = (e&3) + 8*(e>>2) + 4*(lane>>5)
    if constexpr (EPI == 0){
        if (bn < 96){
            const int h = bn / 3, which = bn % 3;
            const float s = slope_for_head(h);
            if (which == 0){
                #pragma unroll
                for (int mt = 0; mt < 2; mt++)
                #pragma unroll
                for (int nt = 0; nt < 2; nt++)
                #pragma unroll
                for (int e = 0; e < 16; e++){
                    int pos = bm*128 + wm*64 + mt*32 + (e&3) + 8*(e>>2) + 4*half;
                    int d = wn*64 + nt*32 + ml;
                    float x = acc[mt][nt][e];
                    float sv = x / (1.f + __expf(-x));
                    qbuf[((size_t)h*SEQ + pos)*HD + d] = (__bf16)sv;
                }
            } else if (which == 1){
                const float es1 = __expf(s), es2 = es1*es1, es3 = es2*es1;
                #pragma unroll
                for (int mt = 0; mt < 2; mt++)
                #pragma unroll
                for (int nt = 0; nt < 2; nt++){
                    const int d = wn*64 + nt*32 + ml;
                    #pragma unroll
                    for (int gq = 0; gq < 4; gq++){
                        int pos0 = bm*128 + wm*64 + mt*32 + 8*gq + 4*half;
                        float d0 = __expf(-s*(float)(255 - (pos0 & 255)));
                        float dd[4] = {d0, d0*es1, d0*es2, d0*es3};
                        bf16x4 pk;
                        #pragma unroll
                        for (int c = 0; c < 4; c++){
                            float x = acc[mt][nt][gq*4 + c];
                            float sv = x / (1.f + __expf(-x));
                            kbuf[((size_t)h*SEQ + pos0 + c)*HD + d] = (__bf16)sv;
                            pk[c] = (__bf16)(sv*dd[c]);
                        }
                        *(bf16x4*)(kT + ((size_t)h*HD + d)*SEQ + pos0) = pk;
                    }
                }
            } else {
                #pragma unroll
                for (int mt = 0; mt < 2; mt++)
                #pragma unroll
                for (int nt = 0; nt < 2; nt++){
                    const int d = wn*64 + nt*32 + ml;
                    #pragma unroll
                    for (int gq = 0; gq < 4; gq++){
                        int pos0 = bm*128 + wm*64 + mt*32 + 8*gq + 4*half;
                        bf16x4 pv;
                        #pragma unroll
                        for (int c = 0; c < 4; c++){
                            float x = acc[mt][nt][gq*4 + c];
                            pv[c] = (__bf16)(x / (1.f + __expf(-x)));
                        }
                        *(bf16x4*)(vT + ((size_t)h*HD + d)*SEQ + pos0) = pv;
                    }
                }
            }
        } else {
            const int col0 = (bn - 96)*128;
            #pragma unroll
            for (int mt = 0; mt < 2; mt++)
            #pragma unroll
            for (int nt = 0; nt < 2; nt++)
            #pragma unroll
            for (int e = 0; e < 16; e++){
                int row = bm*128 + wm*64 + mt*32 + (e&3) + 8*(e>>2) + 4*half;
                int col = col0 + wn*64 + nt*32 + ml;
                float x = acc[mt][nt][e];
                sgate[(size_t)row*NINNER + col] = (__bf16)(1.f/(1.f + __expf(-x)));
            }
        }
    } else {
        #pragma unroll
        for (int mt = 0; mt < 2; mt++)
        #pragma unroll
        for (int nt = 0; nt < 2; nt++)
        #pragma unroll
        for (int e = 0; e < 16; e++){
            int row = bm*128 + wm*64 + mt*32 + (e&3) + 8*(e>>2) + 4*half;
            int col = bn*128 + wn*64 + nt*32 + ml;
            Cf[(size_t)row*N + col] = acc[mt][nt][e];
        }
    }
}

// ---------------------------------------------------------------- pass A: kvbT[h][b][e][d] = sum_i v[i][e]*kdec[i][d]
__global__ __launch_bounds__(256,2)
void pass_a(const __bf16* __restrict__ vT, const __bf16* __restrict__ kT,
            float* __restrict__ kvbT)
{
    __shared__ __align__(16) __bf16 a_lds[128*64];
    __shared__ __align__(16) __bf16 b_lds[128*64];
    const int b = blockIdx.x, h = blockIdx.y;
    const int tid = threadIdx.x, lane = tid & 63, w = tid >> 6;
    const int lr = lane & 15, quad = lane >> 4;
    const int wm = w & 1, wn = w >> 1;

    f32x4 acc[4][4];
    #pragma unroll
    for (int i = 0; i < 4; i++)
        #pragma unroll
        for (int j = 0; j < 4; j++) acc[i][j] = (f32x4){0.f,0.f,0.f,0.f};

    const int r8 = lane >> 3;
    const int qs = (lane & 7) ^ r8;
    const int sw = lr & 7;
    const __bf16* Abase = vT + (size_t)h*HD*SEQ + (size_t)b*BLK;
    const __bf16* Bbase = kT + (size_t)h*HD*SEQ + (size_t)b*BLK;

    for (int kb = 0; kb < BLK; kb += 64){
        #pragma unroll
        for (int t = 0; t < 4; t++){
            int ch = t*4 + w;
            gld16(a_lds + ch*512, Abase + (size_t)(ch*8 + r8)*SEQ + kb + qs*8);
            gld16(b_lds + ch*512, Bbase + (size_t)(ch*8 + r8)*SEQ + kb + qs*8);
        }
        __syncthreads();
        #pragma unroll
        for (int kk = 0; kk < 2; kk++){
            bf16x8 af[4];
            #pragma unroll
            for (int mt = 0; mt < 4; mt++)
                af[mt] = *(const bf16x8*)&a_lds[(wm*64 + mt*16 + lr)*64 + (((kk*4+quad) ^ sw)*8)];
            #pragma unroll
            for (int nt = 0; nt < 4; nt++){
                bf16x8 bfv = *(const bf16x8*)&b_lds[(wn*64 + nt*16 + lr)*64 + (((kk*4+quad) ^ sw)*8)];
                #pragma unroll
                for (int mt = 0; mt < 4; mt++)
                    acc[mt][nt] = MFMA16(af[mt], bfv, acc[mt][nt]);
            }
        }
        __syncthreads();
    }
    float* outp = kvbT + (size_t)(h*NB + b)*HD*HD;
    #pragma unroll
    for (int mt = 0; mt < 4; mt++)
    #pragma unroll
    for (int nt = 0; nt < 4; nt++)
    #pragma unroll
    for (int r = 0; r < 4; r++){
        int row = wm*64 + mt*16 + quad*4 + r;   // e
        int col = wn*64 + nt*16 + lr;           // d
        outp[(size_t)row*HD + col] = acc[mt][nt][r];
    }
}

// ---------------------------------------------------------------- pass B: prefix scan (software-pipelined)
__global__ __launch_bounds__(256)
void scan_kv(const float* __restrict__ kvbT, const float* __restrict__ kv0,
             __bf16* __restrict__ kvsT)
{
    const int chunk = blockIdx.x;   // 0..7
    const int h = blockIdx.y;
    const int t = threadIdx.x;
    const float s = slope_for_head(h);
    const float lam = __expf(-s*(float)BLK);
    const int le0 = chunk*2048;
    float st[8], cur[8], nxt[8];
    #pragma unroll
    for (int j = 0; j < 8; j++){
        int le = le0 + t + 256*j;
        int e = le >> 7, d = le & 127;
        st[j] = kv0[(size_t)h*HD*HD + (size_t)d*HD + e];
    }
    size_t base0 = (size_t)(h*NB)*HD*HD + le0;
    #pragma unroll
    for (int j = 0; j < 8; j++) cur[j] = kvbT[base0 + t + 256*j];
    for (int b = 0; b < NB; b++){
        size_t base = (size_t)(h*NB + b)*HD*HD + le0;
        #pragma unroll
        for (int j = 0; j < 8; j++) kvsT[base + t + 256*j] = (__bf16)st[j];
        if (b < NB-1){
            size_t nb = base + (size_t)HD*HD;
            #pragma unroll
            for (int j = 0; j < 8; j++) nxt[j] = kvbT[nb + t + 256*j];
        }
        #pragma unroll
        for (int j = 0; j < 8; j++){ st[j] = lam*st[j] + cur[j]; cur[j] = nxt[j]; }
    }
}

// ---------------------------------------------------------------- pass C: out = (q*qdec)@kv + (diag_decay*(q@k^T))@v
__global__ __launch_bounds__(256,2)
void pass_c(const __bf16* __restrict__ qbuf, const __bf16* __restrict__ kbuf,
            const __bf16* __restrict__ vT, const __bf16* __restrict__ kvsT,
            float* __restrict__ attn)
{
    __shared__ __align__(16) __bf16 p_lds[4][32*72];
    const int rb = blockIdx.x & 1, b = blockIdx.x >> 1, h = blockIdx.y;
    const float s = slope_for_head(h);
    const int tid = threadIdx.x, lane = tid & 63, w = tid >> 6;
    const int lr = lane & 15, quad = lane >> 4;
    const int R0 = rb*128 + w*32;

    const __bf16* qh  = qbuf + (size_t)h*SEQ*HD + (size_t)b*BLK*HD;
    const __bf16* kh  = kbuf + (size_t)h*SEQ*HD + (size_t)b*BLK*HD;
    const __bf16* vh  = vT   + (size_t)h*HD*SEQ + (size_t)b*BLK;
    const __bf16* kvh = kvsT + (size_t)(h*NB + b)*HD*HD;

    f32x4 acc[2][8];
    #pragma unroll
    for (int i = 0; i < 2; i++)
        #pragma unroll
        for (int j = 0; j < 8; j++) acc[i][j] = (f32x4){0.f,0.f,0.f,0.f};

    bf16x8 qf[4][2];
    #pragma unroll
    for (int ks = 0; ks < 4; ks++)
        #pragma unroll
        for (int mt = 0; mt < 2; mt++)
            qf[ks][mt] = *(const bf16x8*)(qh + (size_t)(R0 + mt*16 + lr)*HD + ks*32 + quad*8);

    float qdec[2];
    #pragma unroll
    for (int mt = 0; mt < 2; mt++)
        qdec[mt] = __expf(-s*(float)(R0 + mt*16 + lr + 1));
    #pragma unroll
    for (int ks = 0; ks < 4; ks++){
        bf16x8 saf[2];
        #pragma unroll
        for (int mt = 0; mt < 2; mt++)
            #pragma unroll
            for (int j = 0; j < 8; j++) saf[mt][j] = (__bf16)((float)qf[ks][mt][j]*qdec[mt]);
        #pragma unroll
        for (int nt = 0; nt < 8; nt++){
            bf16x8 bv = *(const bf16x8*)(kvh + (size_t)(nt*16 + lr)*HD + ks*32 + quad*8);
            #pragma unroll
            for (int mt = 0; mt < 2; mt++) acc[mt][nt] = MFMA16(saf[mt], bv, acc[mt][nt]);
        }
    }

    float colf[4];
    #pragma unroll
    for (int nt = 0; nt < 4; nt++)
        colf[nt] = __expf(-s*(float)(63 - nt*16 - lr));
    const int cmax = (R0 + 31) >> 6;
    for (int c = 0; c <= cmax; c++){
        f32x4 qk[2][4];
        #pragma unroll
        for (int i = 0; i < 2; i++)
            #pragma unroll
            for (int j = 0; j < 4; j++) qk[i][j] = (f32x4){0.f,0.f,0.f,0.f};
        #pragma unroll
        for (int ks = 0; ks < 4; ks++){
            #pragma unroll
            for (int nt = 0; nt < 4; nt++){
                bf16x8 kf = *(const bf16x8*)(kh + (size_t)(c*64 + nt*16 + lr)*HD + ks*32 + quad*8);
                #pragma unroll
                for (int mt = 0; mt < 2; mt++) qk[mt][nt] = MFMA16(qf[ks][mt], kf, qk[mt][nt]);
            }
        }
        float rowf[2][4];
        #pragma unroll
        for (int mt = 0; mt < 2; mt++)
            #pragma unroll
            for (int r = 0; r < 4; r++)
                rowf[mt][r] = __expf(-s*(float)(R0 + mt*16 + quad*4 + r - c*64 - 63));
        #pragma unroll
        for (int mt = 0; mt < 2; mt++)
        #pragma unroll
        for (int nt = 0; nt < 4; nt++)
        #pragma unroll
        for (int r = 0; r < 4; r++){
            int i  = R0 + mt*16 + quad*4 + r;
            int jj = c*64 + nt*16 + lr;
            float dv = (i >= jj) ? rowf[mt][r]*colf[nt] : 0.f;
            p_lds[w][(mt*16 + quad*4 + r)*72 + nt*16 + lr] = (__bf16)(qk[mt][nt][r]*dv);
        }
        #pragma unroll
        for (int ks2 = 0; ks2 < 2; ks2++){
            bf16x8 pf[2];
            #pragma unroll
            for (int mt = 0; mt < 2; mt++)
                pf[mt] = *(const bf16x8*)&p_lds[w][(mt*16 + lr)*72 + ks2*32 + quad*8];
            #pragma unroll
            for (int nt = 0; nt < 8; nt++){
                bf16x8 vf = *(const bf16x8*)(vh + (size_t)(nt*16 + lr)*SEQ + c*64 + ks2*32 + quad*8);
                #pragma unroll
                for (int mt = 0; mt < 2; mt++) acc[mt][nt] = MFMA16(pf[mt], vf, acc[mt][nt]);
            }
        }
    }

    #pragma unroll
    for (int mt = 0; mt < 2; mt++)
    #pragma unroll
    for (int nt = 0; nt < 8; nt++)
    #pragma unroll
    for (int r = 0; r < 4; r++){
        int pos = b*BLK + R0 + mt*16 + quad*4 + r;
        int e = nt*16 + lr;
        attn[(size_t)pos*NINNER + h*HD + e] = acc[mt][nt][r];
    }
}

// ---------------------------------------------------------------- rmsnorm * sigmoid(gate) -> bf16
__global__ __launch_bounds__(256)
void rmsgate(const float* __restrict__ attn, const __bf16* __restrict__ sg,
             const float* __restrict__ nw, __bf16* __restrict__ h2)
{
    const int row = blockIdx.x, tid = threadIdx.x;
    const float* x = attn + (size_t)row*NINNER;
    float4 xs[4];
    float ss = 0.f;
    #pragma unroll
    for (int i = 0; i < 4; i++){
        xs[i] = *(const float4*)(x + (i*256 + tid)*4);
        ss += xs[i].x*xs[i].x + xs[i].y*xs[i].y + xs[i].z*xs[i].z + xs[i].w*xs[i].w;
    }
    #pragma unroll
    for (int o = 32; o > 0; o >>= 1) ss += __shfl_down(ss, o, 64);
    __shared__ float red[4];
    const int lane = tid & 63, w = tid >> 6;
    if (lane == 0) red[w] = ss;
    __syncthreads();
    float tot = red[0] + red[1] + red[2] + red[3];
    float rs = rsqrtf(tot*(1.f/NINNER) + 1e-5f);
    #pragma unroll
    for (int i = 0; i < 4; i++){
        int idx = (i*256 + tid)*4;
        float4 wv = *(const float4*)(nw + idx);
        bf16x4 sv = *(const bf16x4*)(sg + (size_t)row*NINNER + idx);
        bf16x4 o;
        o[0] = (__bf16)((float)sv[0] * xs[i].x*rs*wv.x);
        o[1] = (__bf16)((float)sv[1] * xs[i].y*rs*wv.y);
        o[2] = (__bf16)((float)sv[2] * xs[i].z*rs*wv.z);
        o[3] = (__bf16)((float)sv[3] * xs[i].w*rs*wv.w);
        *(bf16x4*)(h2 + (size_t)row*NINNER + idx) = o;
    }
}

// ================================================================ launch
extern "C" void kernel_launch(void* const* d_in, const int* in_sizes, int n_in,
                              void* d_out, int out_size, void* d_ws, size_t ws_size,
                              hipStream_t stream) {
    (void)in_sizes; (void)n_in; (void)out_size; (void)ws_size;
    const float* hs    = (const float*)d_in[0];
    const float* kv0   = (const float*)d_in[2];
    const float* Wqkv  = (const float*)d_in[3];
    const float* Wgate = (const float*)d_in[4];
    const float* Wout  = (const float*)d_in[5];
    const float* nw    = (const float*)d_in[6];
    float* out = (float*)d_out;

    char* ws = (char*)d_ws;
    __bf16* WqkvT  = (__bf16*)(ws);
    __bf16* WgateT = (__bf16*)(ws + 50331648);            // contiguous after WqkvT (fused GEMM weight)
    float*  attn   = (float*)(ws);                        // aliases weights after GEMMs consume them
    __bf16* WoutT  = (__bf16*)(ws + 67108864);
    __bf16* hsb    = (__bf16*)(ws + 83886080);
    __bf16* qkvb   = (__bf16*)(ws + 100663296);
    __bf16* qbuf   = qkvb;
    __bf16* kbuf   = qkvb + (size_t)HEADS*SEQ*HD;
    __bf16* h2     = qkvb;                                // alias q after pass_c
    __bf16* kT     = (__bf16*)(ws + 201326592);
    __bf16* vT     = (__bf16*)(ws + 234881024);
    float*  kvbT   = (float*) (ws + 268435456);
    __bf16* kvsT   = (__bf16*)(ws + 301989888);
    __bf16* sgate  = (__bf16*)(ws + 318767104);

    prep_all<<<18432, 256, 0, stream>>>(hs, hsb, Wqkv, WqkvT, Wgate, WgateT, Wout, WoutT);

    // fused qkv+gate GEMM, epilogue writes q, k, kT(decayed), vT, sgate
    gemm32<0><<<4096, 256, 0, stream>>>(hsb, WqkvT, nullptr, qbuf, kbuf, kT, vT, sgate,
                                        4096, 16384, 2048);

    pass_a<<<dim3(16, 32), 256, 0, stream>>>(vT, kT, kvbT);
    scan_kv<<<dim3(8, 32), 256, 0, stream>>>(kvbT, kv0, kvsT);
    pass_c<<<dim3(NB*2, 32), 256, 0, stream>>>(qbuf, kbuf, vT, kvsT, attn);

    rmsgate<<<4096, 256, 0, stream>>>(attn, sgate, nw, h2);
    gemm32<2><<<512, 256, 0, stream>>>(h2, WoutT, out, nullptr, nullptr, nullptr, nullptr, nullptr,
                                       4096, 2048, 4096);
}

// Round 4
// 749.053 us; speedup vs baseline: 1.1061x; 1.1061x over previous
//
#include <hip/hip_runtime.h>
#include <hip/hip_bf16.h>
#include <cstdint>
#include <cstddef>

#define SEQ    4096
#define HEADS  32
#define HD     128
#define HIDDEN 2048
#define NINNER 4096
#define BLK    256
#define NB     16

typedef __attribute__((ext_vector_type(8)))  __bf16 bf16x8;
typedef __attribute__((ext_vector_type(4)))  __bf16 bf16x4;
typedef __attribute__((ext_vector_type(4)))  float  f32x4;

#define MFMA16(a,b,c) __builtin_amdgcn_mfma_f32_16x16x32_bf16((a),(b),(c),0,0,0)

typedef __attribute__((address_space(1))) const unsigned int gu32;
typedef __attribute__((address_space(3))) unsigned int lu32;

__device__ __forceinline__ void gld16(void* lds, const void* g){
    __builtin_amdgcn_global_load_lds((gu32*)g, (lu32*)lds, 16, 0, 0);
}

__device__ __forceinline__ float slope_for_head(int h){
    return exp2f(-0.25f*(float)(h+1)) * 1.00001f;
}

// ---------------------------------------------------------------- prep: cast hs + 3 weight transposes, one launch
__device__ __forceinline__ void tcast_block(const float* __restrict__ W, __bf16* __restrict__ Wt,
                                            int K, int N, int bx, int by, __bf16 (*t)[72], int tid){
    const int n0 = bx*64, k0 = by*64;
    const int r = tid >> 4, c4 = tid & 15;
    #pragma unroll
    for (int i = 0; i < 4; i++){
        int k = r + i*16;
        float4 v = *(const float4*)(W + (size_t)(k0 + k)*N + n0 + c4*4);
        t[c4*4+0][k] = (__bf16)v.x;
        t[c4*4+1][k] = (__bf16)v.y;
        t[c4*4+2][k] = (__bf16)v.z;
        t[c4*4+3][k] = (__bf16)v.w;
    }
    __syncthreads();
    #pragma unroll
    for (int j = 0; j < 2; j++){
        int idx = tid + j*256;
        int n = idx >> 3, c8 = idx & 7;
        bf16x8 val = *(const bf16x8*)&t[n][c8*8];
        *(bf16x8*)(Wt + (size_t)(n0 + n)*K + k0 + c8*8) = val;
    }
}

__global__ __launch_bounds__(256)
void prep_all(const float* __restrict__ hs, __bf16* __restrict__ hsb,
              const float* __restrict__ Wqkv, __bf16* __restrict__ WqkvT,
              const float* __restrict__ Wgate, __bf16* __restrict__ WgateT,
              const float* __restrict__ Wout, __bf16* __restrict__ WoutT)
{
    __shared__ __align__(16) __bf16 t[64][72];
    const int tid = threadIdx.x;
    int id = blockIdx.x;
    if (id < 8192){
        int i = (id*256 + tid)*4;
        float4 v = *(const float4*)(hs + i);
        bf16x4 o;
        o[0] = (__bf16)v.x; o[1] = (__bf16)v.y; o[2] = (__bf16)v.z; o[3] = (__bf16)v.w;
        *(bf16x4*)(hsb + i) = o;
    } else if (id < 14336){
        int j = id - 8192;
        tcast_block(Wqkv, WqkvT, 2048, 12288, j % 192, j / 192, t, tid);
    } else if (id < 16384){
        int j = id - 14336;
        tcast_block(Wgate, WgateT, 2048, 4096, j % 64, j / 64, t, tid);
    } else {
        int j = id - 16384;
        tcast_block(Wout, WoutT, 4096, 2048, j % 32, j / 32, t, tid);
    }
}

// ---------------------------------------------------------------- GEMM (16x16x32 MFMA) C = A @ Bt^T
// A [M][K] bf16, Bt [N][K] bf16. 128x128 tile, BK=64, XOR-swizzled LDS (0-conflict verified R2).
// Grid flat, bm fastest within 16-wide bn panels (L2 window: A-full + 8MB of B).
// EPI 0: fused qkv+gate, N=16384. bn<96: silu -> q, k (+decayed kT), vT; bn>=96: sigmoid -> sgate.
// EPI 2: f32 [M][N].
template<int EPI>
__global__ __launch_bounds__(256,2)
void gemm_bt(const __bf16* __restrict__ A, const __bf16* __restrict__ Bt,
             float* __restrict__ Cf,
             __bf16* __restrict__ qbuf, __bf16* __restrict__ kbuf,
             __bf16* __restrict__ kT,   __bf16* __restrict__ vT,
             __bf16* __restrict__ sgate,
             int M, int N, int K)
{
    __shared__ __align__(16) __bf16 a_lds[128*64];
    __shared__ __align__(16) __bf16 b_lds[128*64];
    const int tid  = threadIdx.x;
    const int lane = tid & 63;
    const int w    = tid >> 6;
    const int lr   = lane & 15;
    const int quad = lane >> 4;
    const int wm = w & 1, wn = w >> 1;

    int bm, bn;
    if constexpr (EPI == 0){
        int id = blockIdx.x;
        bm = id & 31;
        bn = (id >> 9)*16 + ((id >> 5) & 15);
    } else {
        bm = blockIdx.x & 31;
        bn = blockIdx.x >> 5;
    }

    f32x4 acc[4][4];
    #pragma unroll
    for (int i = 0; i < 4; i++)
        #pragma unroll
        for (int j = 0; j < 4; j++) acc[i][j] = (f32x4){0.f,0.f,0.f,0.f};

    const int r8 = lane >> 3;            // staging row within 8-row chunk
    const int qs = (lane & 7) ^ r8;      // XOR-swizzled granule
    const int sw = lr & 7;
    const __bf16* Abase = A  + (size_t)bm*128*K;
    const __bf16* Bbase = Bt + (size_t)bn*128*K;

    for (int kb = 0; kb < K; kb += 64){
        #pragma unroll
        for (int t = 0; t < 4; t++){
            int ch = t*4 + w;   // 0..15, 8 rows each
            gld16(a_lds + ch*512, Abase + (size_t)(ch*8 + r8)*K + kb + qs*8);
            gld16(b_lds + ch*512, Bbase + (size_t)(ch*8 + r8)*K + kb + qs*8);
        }
        __syncthreads();
        #pragma unroll
        for (int kk = 0; kk < 2; kk++){
            bf16x8 af[4];
            #pragma unroll
            for (int mt = 0; mt < 4; mt++)
                af[mt] = *(const bf16x8*)&a_lds[(wm*64 + mt*16 + lr)*64 + (((kk*4+quad) ^ sw)*8)];
            #pragma unroll
            for (int nt = 0; nt < 4; nt++){
                bf16x8 bfv = *(const bf16x8*)&b_lds[(wn*64 + nt*16 + lr)*64 + (((kk*4+quad) ^ sw)*8)];
                #pragma unroll
                for (int mt = 0; mt < 4; mt++)
                    acc[mt][nt] = MFMA16(af[mt], bfv, acc[mt][nt]);
            }
        }
        __syncthreads();
    }

    // C/D layout: col = lane&15, row = quad*4 + r  (each lane: 4 consecutive rows, fixed col)
    if constexpr (EPI == 0){
        if (bn < 96){
            const int h = bn / 3, which = bn % 3;
            const float s = slope_for_head(h);
            if (which == 0){
                #pragma unroll
                for (int mt = 0; mt < 4; mt++)
                #pragma unroll
                for (int nt = 0; nt < 4; nt++)
                #pragma unroll
                for (int r = 0; r < 4; r++){
                    int pos = bm*128 + wm*64 + mt*16 + quad*4 + r;
                    int d = wn*64 + nt*16 + lr;
                    float x = acc[mt][nt][r];
                    float sv = x / (1.f + __expf(-x));
                    qbuf[((size_t)h*SEQ + pos)*HD + d] = (__bf16)sv;
                }
            } else if (which == 1){
                const float es1 = __expf(s);
                #pragma unroll
                for (int mt = 0; mt < 4; mt++)
                #pragma unroll
                for (int nt = 0; nt < 4; nt++){
                    const int d = wn*64 + nt*16 + lr;
                    const int pos0 = bm*128 + wm*64 + mt*16 + quad*4;
                    float dec = __expf(-s*(float)(255 - (pos0 & 255)));
                    bf16x4 pk;
                    #pragma unroll
                    for (int r = 0; r < 4; r++){
                        float x = acc[mt][nt][r];
                        float sv = x / (1.f + __expf(-x));
                        kbuf[((size_t)h*SEQ + pos0 + r)*HD + d] = (__bf16)sv;
                        pk[r] = (__bf16)(sv*dec);
                        dec *= es1;
                    }
                    *(bf16x4*)(kT + ((size_t)h*HD + d)*SEQ + pos0) = pk;
                }
            } else {
                #pragma unroll
                for (int mt = 0; mt < 4; mt++)
                #pragma unroll
                for (int nt = 0; nt < 4; nt++){
                    const int d = wn*64 + nt*16 + lr;
                    const int pos0 = bm*128 + wm*64 + mt*16 + quad*4;
                    bf16x4 pv;
                    #pragma unroll
                    for (int r = 0; r < 4; r++){
                        float x = acc[mt][nt][r];
                        pv[r] = (__bf16)(x / (1.f + __expf(-x)));
                    }
                    *(bf16x4*)(vT + ((size_t)h*HD + d)*SEQ + pos0) = pv;
                }
            }
        } else {
            const int col0 = (bn - 96)*128;
            #pragma unroll
            for (int mt = 0; mt < 4; mt++)
            #pragma unroll
            for (int nt = 0; nt < 4; nt++)
            #pragma unroll
            for (int r = 0; r < 4; r++){
                int row = bm*128 + wm*64 + mt*16 + quad*4 + r;
                int col = col0 + wn*64 + nt*16 + lr;
                float x = acc[mt][nt][r];
                sgate[(size_t)row*NINNER + col] = (__bf16)(1.f/(1.f + __expf(-x)));
            }
        }
    } else {
        #pragma unroll
        for (int mt = 0; mt < 4; mt++)
        #pragma unroll
        for (int nt = 0; nt < 4; nt++)
        #pragma unroll
        for (int r = 0; r < 4; r++){
            int row = bm*128 + wm*64 + mt*16 + quad*4 + r;
            int col = bn*128 + wn*64 + nt*16 + lr;
            Cf[(size_t)row*N + col] = acc[mt][nt][r];
        }
    }
}

// ---------------------------------------------------------------- pass A: kvbT[h][b][e][d] = sum_i v[i][e]*kdec[i][d]
__global__ __launch_bounds__(256,2)
void pass_a(const __bf16* __restrict__ vT, const __bf16* __restrict__ kT,
            float* __restrict__ kvbT)
{
    __shared__ __align__(16) __bf16 a_lds[128*64];
    __shared__ __align__(16) __bf16 b_lds[128*64];
    const int b = blockIdx.x, h = blockIdx.y;
    const int tid = threadIdx.x, lane = tid & 63, w = tid >> 6;
    const int lr = lane & 15, quad = lane >> 4;
    const int wm = w & 1, wn = w >> 1;

    f32x4 acc[4][4];
    #pragma unroll
    for (int i = 0; i < 4; i++)
        #pragma unroll
        for (int j = 0; j < 4; j++) acc[i][j] = (f32x4){0.f,0.f,0.f,0.f};

    const int r8 = lane >> 3;
    const int qs = (lane & 7) ^ r8;
    const int sw = lr & 7;
    const __bf16* Abase = vT + (size_t)h*HD*SEQ + (size_t)b*BLK;
    const __bf16* Bbase = kT + (size_t)h*HD*SEQ + (size_t)b*BLK;

    for (int kb = 0; kb < BLK; kb += 64){
        #pragma unroll
        for (int t = 0; t < 4; t++){
            int ch = t*4 + w;
            gld16(a_lds + ch*512, Abase + (size_t)(ch*8 + r8)*SEQ + kb + qs*8);
            gld16(b_lds + ch*512, Bbase + (size_t)(ch*8 + r8)*SEQ + kb + qs*8);
        }
        __syncthreads();
        #pragma unroll
        for (int kk = 0; kk < 2; kk++){
            bf16x8 af[4];
            #pragma unroll
            for (int mt = 0; mt < 4; mt++)
                af[mt] = *(const bf16x8*)&a_lds[(wm*64 + mt*16 + lr)*64 + (((kk*4+quad) ^ sw)*8)];
            #pragma unroll
            for (int nt = 0; nt < 4; nt++){
                bf16x8 bfv = *(const bf16x8*)&b_lds[(wn*64 + nt*16 + lr)*64 + (((kk*4+quad) ^ sw)*8)];
                #pragma unroll
                for (int mt = 0; mt < 4; mt++)
                    acc[mt][nt] = MFMA16(af[mt], bfv, acc[mt][nt]);
            }
        }
        __syncthreads();
    }
    float* outp = kvbT + (size_t)(h*NB + b)*HD*HD;
    #pragma unroll
    for (int mt = 0; mt < 4; mt++)
    #pragma unroll
    for (int nt = 0; nt < 4; nt++)
    #pragma unroll
    for (int r = 0; r < 4; r++){
        int row = wm*64 + mt*16 + quad*4 + r;   // e
        int col = wn*64 + nt*16 + lr;           // d
        outp[(size_t)row*HD + col] = acc[mt][nt][r];
    }
}

// ---------------------------------------------------------------- pass B: prefix scan (software-pipelined)
__global__ __launch_bounds__(256)
void scan_kv(const float* __restrict__ kvbT, const float* __restrict__ kv0,
             __bf16* __restrict__ kvsT)
{
    const int chunk = blockIdx.x;   // 0..7
    const int h = blockIdx.y;
    const int t = threadIdx.x;
    const float s = slope_for_head(h);
    const float lam = __expf(-s*(float)BLK);
    const int le0 = chunk*2048;
    float st[8], cur[8], nxt[8];
    #pragma unroll
    for (int j = 0; j < 8; j++){
        int le = le0 + t + 256*j;
        int e = le >> 7, d = le & 127;
        st[j] = kv0[(size_t)h*HD*HD + (size_t)d*HD + e];
    }
    size_t base0 = (size_t)(h*NB)*HD*HD + le0;
    #pragma unroll
    for (int j = 0; j < 8; j++) cur[j] = kvbT[base0 + t + 256*j];
    for (int b = 0; b < NB; b++){
        size_t base = (size_t)(h*NB + b)*HD*HD + le0;
        #pragma unroll
        for (int j = 0; j < 8; j++) kvsT[base + t + 256*j] = (__bf16)st[j];
        if (b < NB-1){
            size_t nb = base + (size_t)HD*HD;
            #pragma unroll
            for (int j = 0; j < 8; j++) nxt[j] = kvbT[nb + t + 256*j];
        }
        #pragma unroll
        for (int j = 0; j < 8; j++){ st[j] = lam*st[j] + cur[j]; cur[j] = nxt[j]; }
    }
}

// ---------------------------------------------------------------- pass C: out = (q*qdec)@kv + (diag_decay*(q@k^T))@v
__global__ __launch_bounds__(256,2)
void pass_c(const __bf16* __restrict__ qbuf, const __bf16* __restrict__ kbuf,
            const __bf16* __restrict__ vT, const __bf16* __restrict__ kvsT,
            float* __restrict__ attn)
{
    __shared__ __align__(16) __bf16 p_lds[4][32*72];
    const int rb = blockIdx.x & 1, b = blockIdx.x >> 1, h = blockIdx.y;
    const float s = slope_for_head(h);
    const int tid = threadIdx.x, lane = tid & 63, w = tid >> 6;
    const int lr = lane & 15, quad = lane >> 4;
    const int R0 = rb*128 + w*32;

    const __bf16* qh  = qbuf + (size_t)h*SEQ*HD + (size_t)b*BLK*HD;
    const __bf16* kh  = kbuf + (size_t)h*SEQ*HD + (size_t)b*BLK*HD;
    const __bf16* vh  = vT   + (size_t)h*HD*SEQ + (size_t)b*BLK;
    const __bf16* kvh = kvsT + (size_t)(h*NB + b)*HD*HD;

    f32x4 acc[2][8];
    #pragma unroll
    for (int i = 0; i < 2; i++)
        #pragma unroll
        for (int j = 0; j < 8; j++) acc[i][j] = (f32x4){0.f,0.f,0.f,0.f};

    bf16x8 qf[4][2];
    #pragma unroll
    for (int ks = 0; ks < 4; ks++)
        #pragma unroll
        for (int mt = 0; mt < 2; mt++)
            qf[ks][mt] = *(const bf16x8*)(qh + (size_t)(R0 + mt*16 + lr)*HD + ks*32 + quad*8);

    float qdec[2];
    #pragma unroll
    for (int mt = 0; mt < 2; mt++)
        qdec[mt] = __expf(-s*(float)(R0 + mt*16 + lr + 1));
    #pragma unroll
    for (int ks = 0; ks < 4; ks++){
        bf16x8 saf[2];
        #pragma unroll
        for (int mt = 0; mt < 2; mt++)
            #pragma unroll
            for (int j = 0; j < 8; j++) saf[mt][j] = (__bf16)((float)qf[ks][mt][j]*qdec[mt]);
        #pragma unroll
        for (int nt = 0; nt < 8; nt++){
            bf16x8 bv = *(const bf16x8*)(kvh + (size_t)(nt*16 + lr)*HD + ks*32 + quad*8);
            #pragma unroll
            for (int mt = 0; mt < 2; mt++) acc[mt][nt] = MFMA16(saf[mt], bv, acc[mt][nt]);
        }
    }

    float colf[4];
    #pragma unroll
    for (int nt = 0; nt < 4; nt++)
        colf[nt] = __expf(-s*(float)(63 - nt*16 - lr));
    const int cmax = (R0 + 31) >> 6;
    for (int c = 0; c <= cmax; c++){
        f32x4 qk[2][4];
        #pragma unroll
        for (int i = 0; i < 2; i++)
            #pragma unroll
            for (int j = 0; j < 4; j++) qk[i][j] = (f32x4){0.f,0.f,0.f,0.f};
        #pragma unroll
        for (int ks = 0; ks < 4; ks++){
            #pragma unroll
            for (int nt = 0; nt < 4; nt++){
                bf16x8 kf = *(const bf16x8*)(kh + (size_t)(c*64 + nt*16 + lr)*HD + ks*32 + quad*8);
                #pragma unroll
                for (int mt = 0; mt < 2; mt++) qk[mt][nt] = MFMA16(qf[ks][mt], kf, qk[mt][nt]);
            }
        }
        float rowf[2][4];
        #pragma unroll
        for (int mt = 0; mt < 2; mt++)
            #pragma unroll
            for (int r = 0; r < 4; r++)
                rowf[mt][r] = __expf(-s*(float)(R0 + mt*16 + quad*4 + r - c*64 - 63));
        #pragma unroll
        for (int mt = 0; mt < 2; mt++)
        #pragma unroll
        for (int nt = 0; nt < 4; nt++)
        #pragma unroll
        for (int r = 0; r < 4; r++){
            int i  = R0 + mt*16 + quad*4 + r;
            int jj = c*64 + nt*16 + lr;
            float dv = (i >= jj) ? rowf[mt][r]*colf[nt] : 0.f;
            p_lds[w][(mt*16 + quad*4 + r)*72 + nt*16 + lr] = (__bf16)(qk[mt][nt][r]*dv);
        }
        #pragma unroll
        for (int ks2 = 0; ks2 < 2; ks2++){
            bf16x8 pf[2];
            #pragma unroll
            for (int mt = 0; mt < 2; mt++)
                pf[mt] = *(const bf16x8*)&p_lds[w][(mt*16 + lr)*72 + ks2*32 + quad*8];
            #pragma unroll
            for (int nt = 0; nt < 8; nt++){
                bf16x8 vf = *(const bf16x8*)(vh + (size_t)(nt*16 + lr)*SEQ + c*64 + ks2*32 + quad*8);
                #pragma unroll
                for (int mt = 0; mt < 2; mt++) acc[mt][nt] = MFMA16(pf[mt], vf, acc[mt][nt]);
            }
        }
    }

    #pragma unroll
    for (int mt = 0; mt < 2; mt++)
    #pragma unroll
    for (int nt = 0; nt < 8; nt++)
    #pragma unroll
    for (int r = 0; r < 4; r++){
        int pos = b*BLK + R0 + mt*16 + quad*4 + r;
        int e = nt*16 + lr;
        attn[(size_t)pos*NINNER + h*HD + e] = acc[mt][nt][r];
    }
}

// ---------------------------------------------------------------- rmsnorm * sigmoid(gate) -> bf16
__global__ __launch_bounds__(256)
void rmsgate(const float* __restrict__ attn, const __bf16* __restrict__ sg,
             const float* __restrict__ nw, __bf16* __restrict__ h2)
{
    const int row = blockIdx.x, tid = threadIdx.x;
    const float* x = attn + (size_t)row*NINNER;
    float4 xs[4];
    float ss = 0.f;
    #pragma unroll
    for (int i = 0; i < 4; i++){
        xs[i] = *(const float4*)(x + (i*256 + tid)*4);
        ss += xs[i].x*xs[i].x + xs[i].y*xs[i].y + xs[i].z*xs[i].z + xs[i].w*xs[i].w;
    }
    #pragma unroll
    for (int o = 32; o > 0; o >>= 1) ss += __shfl_down(ss, o, 64);
    __shared__ float red[4];
    const int lane = tid & 63, w = tid >> 6;
    if (lane == 0) red[w] = ss;
    __syncthreads();
    float tot = red[0] + red[1] + red[2] + red[3];
    float rs = rsqrtf(tot*(1.f/NINNER) + 1e-5f);
    #pragma unroll
    for (int i = 0; i < 4; i++){
        int idx = (i*256 + tid)*4;
        float4 wv = *(const float4*)(nw + idx);
        bf16x4 sv = *(const bf16x4*)(sg + (size_t)row*NINNER + idx);
        bf16x4 o;
        o[0] = (__bf16)((float)sv[0] * xs[i].x*rs*wv.x);
        o[1] = (__bf16)((float)sv[1] * xs[i].y*rs*wv.y);
        o[2] = (__bf16)((float)sv[2] * xs[i].z*rs*wv.z);
        o[3] = (__bf16)((float)sv[3] * xs[i].w*rs*wv.w);
        *(bf16x4*)(h2 + (size_t)row*NINNER + idx) = o;
    }
}

// ================================================================ launch
extern "C" void kernel_launch(void* const* d_in, const int* in_sizes, int n_in,
                              void* d_out, int out_size, void* d_ws, size_t ws_size,
                              hipStream_t stream) {
    (void)in_sizes; (void)n_in; (void)out_size; (void)ws_size;
    const float* hs    = (const float*)d_in[0];
    const float* kv0   = (const float*)d_in[2];
    const float* Wqkv  = (const float*)d_in[3];
    const float* Wgate = (const float*)d_in[4];
    const float* Wout  = (const float*)d_in[5];
    const float* nw    = (const float*)d_in[6];
    float* out = (float*)d_out;

    char* ws = (char*)d_ws;
    __bf16* WqkvT  = (__bf16*)(ws);
    __bf16* WgateT = (__bf16*)(ws + 50331648);            // contiguous after WqkvT (fused GEMM weight)
    float*  attn   = (float*)(ws);                        // aliases weights after GEMMs consume them
    __bf16* WoutT  = (__bf16*)(ws + 67108864);
    __bf16* hsb    = (__bf16*)(ws + 83886080);
    __bf16* qkvb   = (__bf16*)(ws + 100663296);
    __bf16* qbuf   = qkvb;
    __bf16* kbuf   = qkvb + (size_t)HEADS*SEQ*HD;
    __bf16* h2     = qkvb;                                // alias q after pass_c
    __bf16* kT     = (__bf16*)(ws + 201326592);
    __bf16* vT     = (__bf16*)(ws + 234881024);
    float*  kvbT   = (float*) (ws + 268435456);
    __bf16* kvsT   = (__bf16*)(ws + 301989888);
    __bf16* sgate  = (__bf16*)(ws + 318767104);

    prep_all<<<18432, 256, 0, stream>>>(hs, hsb, Wqkv, WqkvT, Wgate, WgateT, Wout, WoutT);

    // fused qkv+gate GEMM, epilogue writes q, k, kT(decayed), vT, sgate
    gemm_bt<0><<<4096, 256, 0, stream>>>(hsb, WqkvT, nullptr, qbuf, kbuf, kT, vT, sgate,
                                         4096, 16384, 2048);

    pass_a<<<dim3(16, 32), 256, 0, stream>>>(vT, kT, kvbT);
    scan_kv<<<dim3(8, 32), 256, 0, stream>>>(kvbT, kv0, kvsT);
    pass_c<<<dim3(NB*2, 32), 256, 0, stream>>>(qbuf, kbuf, vT, kvsT, attn);

    rmsgate<<<4096, 256, 0, stream>>>(attn, sgate, nw, h2);
    gemm_bt<2><<<512, 256, 0, stream>>>(h2, WoutT, out, nullptr, nullptr, nullptr, nullptr, nullptr,
                                        4096, 2048, 4096);
}